// Round 17
// baseline (248.910 us; speedup 1.0000x reference)
//
#include <hip/hip_runtime.h>
#include <hip/hip_bf16.h>
#include <stdint.h>

// ---------------------------------------------------------------------------
// MultiHeadAttention forward, MI355X bf16-MFMA implementation.
//   x[4,2048,1024] @ W_qkv[1024,3072] + b  -> Q,K -> [B,H,T,64], V -> [B,H,64,T]
//   flash attention per (b,h), T=2048, d=64 -> ctx [B,T,1024] bf16
//   ctx @ W_out + b_out -> out fp32 [4,2048,1024]
// Round 17: FRAGMENT-ORDER LDS staging (both kernels). The old row-major+XOR
// layout still had 8-way bank conflicts on fragment reads (bank = f(slot)
// only, 8 groups x 4 banks for 64 lanes). Since global_load_lds takes a
// PER-LANE global source, we stage tiles pre-permuted into MFMA fragment
// order [step][half][lane]x16B; inner-loop reads become base + const + lane*16
// -> lane-linear, ZERO bank conflicts, no swizzle math in the loop.
// Math path bit-identical to round-14/16 verified kernel.
// ---------------------------------------------------------------------------

typedef __attribute__((ext_vector_type(8))) short short8;
typedef __attribute__((ext_vector_type(4))) float f32x4;
typedef __attribute__((ext_vector_type(16))) float f32x16;
typedef __attribute__((ext_vector_type(4))) unsigned short ushort4_t;
typedef __attribute__((ext_vector_type(8))) unsigned short ushort8_t;

#define SEQ 2048
#define EDIM 1024
// 0.125 * log2(e): folded into Q so scores arrive in the log2 domain
#define QSCALE 0.18033688011112042f

__device__ __forceinline__ unsigned short f2bf(float x) {
  union { float f; uint32_t u; } v; v.f = x;
  uint32_t r = v.u + 0x7fffu + ((v.u >> 16) & 1u);
  return (unsigned short)(r >> 16);
}

__device__ __forceinline__ uint32_t cvtpk(float lo, float hi) {
  uint32_t r;
  asm("v_cvt_pk_bf16_f32 %0, %1, %2" : "=v"(r) : "v"(lo), "v"(hi));
  return r;
}

__device__ __forceinline__ float exp2_raw(float x) {
  float r;
  asm("v_exp_f32 %0, %1" : "=v"(r) : "v"(x));
  return r;
}

__device__ __forceinline__ void gload_lds16(const void* g, void* l) {
  typedef __attribute__((address_space(1))) const unsigned int gu32;
  typedef __attribute__((address_space(3))) unsigned int lu32;
  __builtin_amdgcn_global_load_lds((gu32*)g, (lu32*)l, 16, 0, 0);
}

// ------------------------- merged prep: fp32->bf16 cvt + 2 weight transposes
// grid 8192: [0,4096) cvt x; [4096,7168) Wqkv^T; [7168,8192) Wout^T
__global__ void k_prep(const float* __restrict__ x,
                       unsigned short* __restrict__ xb,
                       const float* __restrict__ Wq,
                       unsigned short* __restrict__ wqt,
                       const float* __restrict__ Wo,
                       unsigned short* __restrict__ wot) {
  __shared__ float tile[32][33];
  const int id = blockIdx.x;
  if (id < 4096) {
    const int i = id * 256 + threadIdx.x;      // exactly covers 1048576
    const float4* p = ((const float4*)x) + (size_t)i * 2;
    float4 a = p[0], b = p[1];
    ushort8_t v;
    v[0] = f2bf(a.x); v[1] = f2bf(a.y); v[2] = f2bf(a.z); v[3] = f2bf(a.w);
    v[4] = f2bf(b.x); v[5] = f2bf(b.y); v[6] = f2bf(b.z); v[7] = f2bf(b.w);
    ((ushort8_t*)xb)[i] = v;
    return;
  }
  const float* W;
  unsigned short* Wt;
  int N, bx, by;
  if (id < 7168) { W = Wq; Wt = wqt; N = 3072; bx = (id - 4096) % 96; by = (id - 4096) / 96; }
  else           { W = Wo; Wt = wot; N = 1024; bx = (id - 7168) % 32; by = (id - 7168) / 32; }
  const int K = 1024;
  const int c0 = bx * 32, r0 = by * 32;
  const int tx = threadIdx.x & 31, ty = threadIdx.x >> 5;
#pragma unroll
  for (int i = 0; i < 4; ++i) {
    int r = ty + i * 8;
    tile[r][tx] = W[(size_t)(r0 + r) * N + c0 + tx];
  }
  __syncthreads();
#pragma unroll
  for (int i = 0; i < 4; ++i) {
    int r = ty + i * 8;
    Wt[(size_t)(c0 + r) * K + r0 + tx] = f2bf(tile[tx][r]);
  }
}

// --------------------------------------------------------------- 128^2 GEMM
// A [M][1024] bf16, Bt [N][1024] bf16. EPI 0: QKV scatter (Q pre-scaled).
// EPI 1: fp32 out. XCD-aware swizzle (r8). BK=64 two-sub pipeline (r13).
// Fragment-order LDS: slot = [sub][mi][wrr][lane], staged via per-lane global
// source; reads are lane-linear (conflict-free).
template <int EPI, int NBX>
__global__ __launch_bounds__(256, 2) void k_gemm(
    const unsigned short* __restrict__ A, const unsigned short* __restrict__ Bt,
    const float* __restrict__ bias, unsigned short* __restrict__ Qo,
    unsigned short* __restrict__ Ko, unsigned short* __restrict__ VTo,
    float* __restrict__ Out) {
  __shared__ unsigned short As[2 * 8192];   // [buf][sub][mi][wrr][lane] 16B
  __shared__ unsigned short Bs[2 * 8192];
  const int tid = threadIdx.x;
  const int lane = tid & 63, wid = tid >> 6;
  const int wr = wid >> 1, wc = wid & 1;
  const int g = lane >> 4, r = lane & 15;
  const int lid = blockIdx.y * NBX + blockIdx.x;
  const int total = NBX * gridDim.y;
  const int id = (lid & 7) * (total >> 3) + (lid >> 3);
  const int m0 = (id / NBX) * 128, n0 = (id % NBX) * 128;

  // fragment-order staging sources: slot i*256+tid ->
  //   sub=slot>>9, mi=(slot>>7)&3, wrr=(slot>>6)&1, l=slot&63
  //   src = base + (blk0 + wrr*64 + mi*16 + (l&15))*1024 + sub*32 + (l>>4)*8
  const unsigned short* ap[4];
  const unsigned short* bp[4];
#pragma unroll
  for (int i = 0; i < 4; ++i) {
    const int slot = i * 256 + tid;
    const int sub = slot >> 9, mi = (slot >> 7) & 3, wrr = (slot >> 6) & 1;
    const int l = slot & 63;
    const int row = wrr * 64 + mi * 16 + (l & 15);
    const int dof = sub * 32 + (l >> 4) * 8;
    ap[i] = A + (size_t)(m0 + row) * 1024 + dof;
    bp[i] = Bt + (size_t)(n0 + row) * 1024 + dof;
  }
  char* adst = (char*)As + wid * 1024;   // + i*4096, + buf*16384
  char* bdst = (char*)Bs + wid * 1024;

  auto STAGE = [&](int buf) {  // stages one BK=64 K-step; advances sources
    const int bo = buf * 16384;
#pragma unroll
    for (int i = 0; i < 4; ++i) {
      gload_lds16(ap[i], adst + bo + i * 4096);
      gload_lds16(bp[i], bdst + bo + i * 4096);
      ap[i] += 64; bp[i] += 64;
    }
  };

  f32x4 zero4 = {0.f, 0.f, 0.f, 0.f};
  f32x4 acc[4][4];
#pragma unroll
  for (int mi = 0; mi < 4; ++mi)
#pragma unroll
    for (int ni = 0; ni < 4; ++ni) acc[mi][ni] = zero4;

  const int myoff = lane * 16;            // byte offset inside fragment slab
  const char* abase = (const char*)As + wr * 1024 + myoff;
  const char* bbase = (const char*)Bs + wc * 1024 + myoff;

  STAGE(0);
  asm volatile("s_waitcnt vmcnt(0)" ::: "memory");
  __builtin_amdgcn_s_barrier();

  for (int t = 0; t < 16; ++t) {
    const int cur = t & 1;
    if (t < 15) STAGE(cur ^ 1);        // issue next K-step's loads early
    const int co = cur * 16384;
#pragma unroll
    for (int sub = 0; sub < 2; ++sub) {
      short8 af[4], bf[4];
#pragma unroll
      for (int mi = 0; mi < 4; ++mi)
        af[mi] = *(const short8*)(abase + co + sub * 8192 + mi * 2048);
#pragma unroll
      for (int ni = 0; ni < 4; ++ni)
        bf[ni] = *(const short8*)(bbase + co + sub * 8192 + ni * 2048);
#pragma unroll
      for (int mi = 0; mi < 4; ++mi)
#pragma unroll
        for (int ni = 0; ni < 4; ++ni)
          acc[mi][ni] = __builtin_amdgcn_mfma_f32_16x16x32_bf16(
              af[mi], bf[ni], acc[mi][ni], 0, 0, 0);
    }
    asm volatile("s_waitcnt vmcnt(0)" ::: "memory");  // next-step loads landed
    __builtin_amdgcn_s_barrier();
  }

#pragma unroll
  for (int mi = 0; mi < 4; ++mi) {
#pragma unroll
    for (int ni = 0; ni < 4; ++ni) {
      const int n = n0 + wc * 64 + ni * 16 + r;
      const float bv = bias[n];
      const int mbase = m0 + wr * 64 + mi * 16 + g * 4;
      if (EPI == 0) {
        const int sec = n >> 10, e = n & 1023, h = e >> 6, dd = e & 63;
        const int b = mbase >> 11, t = mbase & 2047;
        if (sec == 2) {  // V transposed: [B,H,64,2048], 4 consecutive t packed
          ushort4_t pk;
#pragma unroll
          for (int j = 0; j < 4; ++j) pk[j] = f2bf(acc[mi][ni][j] + bv);
          *(ushort4_t*)&VTo[(((size_t)b * 16 + h) * 64 + dd) * 2048 + t] = pk;
        } else {
          unsigned short* dst = (sec == 0) ? Qo : Ko;
          const float scl = (sec == 0) ? QSCALE : 1.0f;  // fold softmax scale
#pragma unroll
          for (int j = 0; j < 4; ++j)
            dst[(((size_t)b * 16 + h) * 2048 + t + j) * 64 + dd] =
                f2bf((acc[mi][ni][j] + bv) * scl);
        }
      } else {
#pragma unroll
        for (int j = 0; j < 4; ++j)
          Out[(size_t)(mbase + j) * 1024 + n] = acc[mi][ni][j] + bv;
      }
    }
  }
}

// ------------------------------------------------------------ flash attention
// 1D grid 512, XCD-swizzled: xcd=id&7 owns bh in [xcd*8,+8) x 8 qblocks of
// 256 q-rows. 8 waves; wave owns 32 q-rows x ALL 64 keys. KV tile 64,
// double-buffered, issue-early. Fragment-order LDS: K slot [ds][half][lane],
// V slot [ks][half][lane] (16B each) staged via per-lane global source;
// reads are lane-linear (conflict-free, no swizzle math).
// Basis-free softmax; all-ones-MFMA row-sum.
__global__ __launch_bounds__(512, 4) void k_attn(
    const unsigned short* __restrict__ Qg, const unsigned short* __restrict__ Kg,
    const unsigned short* __restrict__ VTg, const int* __restrict__ maskp,
    unsigned short* __restrict__ ctx) {
  __shared__ unsigned short Ks[2 * 4096];     // [buf][ds][half][lane] 16B
  __shared__ unsigned short Vs[2 * 4096];     // [buf][ks][half][lane] 16B
  const int tid = threadIdx.x, lane = tid & 63, wid = tid >> 6;
  const int q = lane & 31, hi = lane >> 5;
  const int id = blockIdx.x;
  const int slot = id >> 3;
  const int bh = (id & 7) * 8 + (slot >> 3);
  const int b = bh >> 4, h = bh & 15;
  const int q0 = (slot & 7) * 256 + wid * 32;
  const int qr = q0 + q;

  const unsigned short* Qb = Qg + (size_t)bh * SEQ * 64;
  const unsigned short* Kb = Kg + (size_t)bh * SEQ * 64;
  const unsigned short* Vb = VTg + (size_t)bh * 64 * SEQ;
  const int* mb = maskp + b * SEQ;

  // fragment-order staging sources: tid -> sds=tid>>7, shalf=(tid>>6)&1,
  // l=tid&63; row = shalf*32+(l&31); dim/key chunk = (sds*2+(l>>5))*8
  const int sds = tid >> 7, shalf = (tid >> 6) & 1, sl_ = tid & 63;
  const int srow = shalf * 32 + (sl_ & 31);
  const int schnk = (sds * 2 + (sl_ >> 5)) * 8;
  const unsigned short* kp0 = Kb + srow * 64 + schnk;            // K[row][dim]
  const unsigned short* vp0 = Vb + (size_t)srow * SEQ + schnk;   // VT[dd][key]
  char* kbase = (char*)Ks + wid * 1024;     // + buf*8192
  char* vbase = (char*)Vs + wid * 1024;

  auto STAGE = [&](int buf) {  // stages the tile the pointers sit at; advances
    const int bo = buf * 8192;
    gload_lds16(kp0, kbase + bo);
    gload_lds16(vp0, vbase + bo);
    kp0 += 64 * 64;                            // next 64 K-rows
    vp0 += 64;                                 // next 64 key-columns
  };

  // Q fragments (B-operand of S^T mfma): lane holds Q[qr][ds*16 + hi*8 + 0..7]
  short8 qf[4];
#pragma unroll
  for (int ds = 0; ds < 4; ++ds)
    qf[ds] = *(const short8*)&Qb[(size_t)qr * 64 + ds * 16 + hi * 8];

  // all-ones bf16 A-fragment (constant matrix => fragment-layout-proof)
  short8 onesf;
#pragma unroll
  for (int j = 0; j < 8; ++j) onesf[j] = (short)0x3F80;

  f32x16 z16 = {0.f,0.f,0.f,0.f,0.f,0.f,0.f,0.f,0.f,0.f,0.f,0.f,0.f,0.f,0.f,0.f};
  f32x16 o0 = z16, o1 = z16;   // O^T[dd][q]: dd = (i&3)+8*(i>>2)+4*hi (+32)
  f32x16 osum = z16;           // every component = sum_k P[q][k] (all rows =)
  const int kb4 = hi * 4;
  const int myoff = lane * 16;               // byte offset in fragment slab

  STAGE(0);
  const int* mptr = mb + lane;
  int mv = mptr[0];
  mptr += 64;

  for (int t = 0; t < 32; ++t) {
    const int cur = t & 1;
    __syncthreads();                       // staging of tile t complete
    int mvn = 1;
    if (t < 31) {                          // issue next tile's loads early
      STAGE(cur ^ 1);
      mvn = mptr[0];
      mptr += 64;
    }
    const unsigned long long bits = __ballot(mv != 0);
    mv = mvn;

    // S^T = K Q^T : lane holds S^T[key][q=lane&31], keys (i&3)+8*(i>>2)+4*hi
    const char* KsB = (const char*)Ks + cur * 8192 + myoff;
    const char* VsB = (const char*)Vs + cur * 8192 + myoff;
    f32x16 c0 = z16, c1 = z16;
    __builtin_amdgcn_s_setprio(1);
#pragma unroll
    for (int ds = 0; ds < 4; ++ds) {
      short8 ka0 = *(const short8*)(KsB + ds * 2048);
      short8 ka1 = *(const short8*)(KsB + ds * 2048 + 1024);
      c0 = __builtin_amdgcn_mfma_f32_32x32x16_bf16(ka0, qf[ds], c0, 0, 0, 0);
      c1 = __builtin_amdgcn_mfma_f32_32x32x16_bf16(ka1, qf[ds], c1, 0, 0, 0);
    }
    __builtin_amdgcn_s_setprio(0);

    // P = exp2(S') directly — scale folded into Q, basis-free (cancels)
#pragma unroll
    for (int i = 0; i < 16; ++i) {
      c0[i] = exp2_raw(c0[i]);
      c1[i] = exp2_raw(c1[i]);
    }
    if (bits != ~0ull) {  // wave-uniform: only when mask has zeros
#pragma unroll
      for (int i = 0; i < 16; ++i) {
        const int k0 = (i & 3) + 8 * (i >> 2) + kb4;
        if (!((bits >> k0) & 1)) c0[i] = 0.f;
        if (!((bits >> (k0 + 32)) & 1)) c1[i] = 0.f;
      }
    }

    // P -> bf16 PV fragments, in-register (cvt_pk + permlane32_swap)
    short8 pf[4];
#pragma unroll
    for (int sub = 0; sub < 2; ++sub) {
      uint32_t w[8];
#pragma unroll
      for (int j = 0; j < 8; ++j)
        w[j] = sub ? cvtpk(c1[2 * j], c1[2 * j + 1])
                   : cvtpk(c0[2 * j], c0[2 * j + 1]);
      asm("v_permlane32_swap_b32 %0, %1" : "+v"(w[0]), "+v"(w[2]));
      asm("v_permlane32_swap_b32 %0, %1" : "+v"(w[1]), "+v"(w[3]));
      asm("v_permlane32_swap_b32 %0, %1" : "+v"(w[4]), "+v"(w[6]));
      asm("v_permlane32_swap_b32 %0, %1" : "+v"(w[5]), "+v"(w[7]));
      union { uint32_t u[4]; short8 s; } ua, ub;
      ua.u[0] = w[0]; ua.u[1] = w[1]; ua.u[2] = w[2]; ua.u[3] = w[3];
      ub.u[0] = w[4]; ub.u[1] = w[5]; ub.u[2] = w[6]; ub.u[3] = w[7];
      pf[sub * 2] = ua.s;
      pf[sub * 2 + 1] = ub.s;
    }

    // O^T += V^T P^T ; row-sum += 1 * P^T (all-ones A => each row = sum_k P)
    __builtin_amdgcn_s_setprio(1);
#pragma unroll
    for (int ks = 0; ks < 4; ++ks) {
      short8 va0 = *(const short8*)(VsB + ks * 2048);
      short8 va1 = *(const short8*)(VsB + ks * 2048 + 1024);
      o0 = __builtin_amdgcn_mfma_f32_32x32x16_bf16(va0, pf[ks], o0, 0, 0, 0);
      o1 = __builtin_amdgcn_mfma_f32_32x32x16_bf16(va1, pf[ks], o1, 0, 0, 0);
      osum = __builtin_amdgcn_mfma_f32_32x32x16_bf16(onesf, pf[ks], osum,
                                                     0, 0, 0);
    }
    __builtin_amdgcn_s_setprio(0);
  }

  // ctx [B,T,1024] bf16: lane writes its query row qr, dd groups of 4
  const float inv = 1.f / osum[0];
#pragma unroll
  for (int ns = 0; ns < 2; ++ns) {
#pragma unroll
    for (int g_ = 0; g_ < 4; ++g_) {
      ushort4_t v4;
#pragma unroll
      for (int e = 0; e < 4; ++e) {
        const float val = (ns ? o1[g_ * 4 + e] : o0[g_ * 4 + e]) * inv;
        v4[e] = f2bf(val);
      }
      *(ushort4_t*)&ctx[((size_t)b * SEQ + qr) * 1024 + h * 64 + ns * 32 +
                        g_ * 8 + hi * 4] = v4;
    }
  }
}

// ---------------------------------------------------------------------------
extern "C" void kernel_launch(void* const* d_in, const int* in_sizes, int n_in,
                              void* d_out, int out_size, void* d_ws,
                              size_t ws_size, hipStream_t stream) {
  const float* x = (const float*)d_in[0];
  const int* mask = (const int*)d_in[1];
  const float* Wqkv = (const float*)d_in[2];
  const float* bqkv = (const float*)d_in[3];
  const float* Wout = (const float*)d_in[4];
  const float* bout = (const float*)d_in[5];
  float* out = (float*)d_out;

  unsigned short* ws = (unsigned short*)d_ws;
  unsigned short* xb = ws;                       // 8388608 (reused as ctx)
  unsigned short* wqt = ws + 8388608;            // 3145728
  unsigned short* wot = ws + 11534336;           // 1048576
  unsigned short* Q = ws + 12582912;             // 8388608
  unsigned short* K = ws + 20971520;             // 8388608
  unsigned short* VT = ws + 29360128;            // 8388608
  unsigned short* ctx = xb;

  k_prep<<<8192, 256, 0, stream>>>(x, xb, Wqkv, wqt, Wout, wot);
  k_gemm<0, 24><<<dim3(24, 64), 256, 0, stream>>>(xb, wqt, bqkv, Q, K, VT,
                                                  nullptr);
  k_attn<<<512, 512, 0, stream>>>(Q, K, VT, mask, ctx);
  k_gemm<1, 8><<<dim3(8, 64), 256, 0, stream>>>(ctx, wot, bout, nullptr,
                                                nullptr, nullptr, out);
}

// Round 18
// 239.193 us; speedup vs baseline: 1.0406x; 1.0406x over previous
//
#include <hip/hip_runtime.h>
#include <hip/hip_bf16.h>
#include <stdint.h>

// ---------------------------------------------------------------------------
// MultiHeadAttention forward, MI355X bf16-MFMA implementation.
//   x[4,2048,1024] @ W_qkv[1024,3072] + b  -> Q,K -> [B,H,T,64], V -> [B,H,64,T]
//   flash attention per (b,h), T=2048, d=64 -> ctx [B,T,1024] bf16
//   ctx @ W_out + b_out -> out fp32 [4,2048,1024]
// Round 18: attn uses REG-STAGED K/V with a dual-conflict-free XOR layout:
//   global load: thread t reads row t>>3, chunk t&7 (coalesced full rows);
//   ds_write to phys slot [(c>>1)*128+(row>>5)*64+(c&1)*32+(row&31)]^(c&7)
//     -> write banks (row&7)^(c&7): conflict-free;
//   ds_read fragment (ds,half): slot ds*128+half*64+(lane^((ds*2+hi)&7))
//     -> read banks cycle all groups: conflict-free.
// (r17 proved conflict-free reads are worth chasing — SQ_LDS_BANK_CONFLICT==0 —
//  but gload_lds fragment-order staging scattered the GLOBAL side; reg-staging
//  decouples the two. Same dbuf barrier structure as verified r14/16.)
// GEMMs and prep identical to round-16 verified (189.4 us config).
// ---------------------------------------------------------------------------

typedef __attribute__((ext_vector_type(8))) short short8;
typedef __attribute__((ext_vector_type(4))) float f32x4;
typedef __attribute__((ext_vector_type(16))) float f32x16;
typedef __attribute__((ext_vector_type(4))) unsigned short ushort4_t;
typedef __attribute__((ext_vector_type(8))) unsigned short ushort8_t;

#define SEQ 2048
#define EDIM 1024
// 0.125 * log2(e): folded into Q so scores arrive in the log2 domain
#define QSCALE 0.18033688011112042f

__device__ __forceinline__ unsigned short f2bf(float x) {
  union { float f; uint32_t u; } v; v.f = x;
  uint32_t r = v.u + 0x7fffu + ((v.u >> 16) & 1u);
  return (unsigned short)(r >> 16);
}

__device__ __forceinline__ uint32_t cvtpk(float lo, float hi) {
  uint32_t r;
  asm("v_cvt_pk_bf16_f32 %0, %1, %2" : "=v"(r) : "v"(lo), "v"(hi));
  return r;
}

__device__ __forceinline__ float exp2_raw(float x) {
  float r;
  asm("v_exp_f32 %0, %1" : "=v"(r) : "v"(x));
  return r;
}

__device__ __forceinline__ void gload_lds16(const void* g, void* l) {
  typedef __attribute__((address_space(1))) const unsigned int gu32;
  typedef __attribute__((address_space(3))) unsigned int lu32;
  __builtin_amdgcn_global_load_lds((gu32*)g, (lu32*)l, 16, 0, 0);
}

// ------------------------- merged prep: fp32->bf16 cvt + 2 weight transposes
// grid 8192: [0,4096) cvt x; [4096,7168) Wqkv^T; [7168,8192) Wout^T
__global__ void k_prep(const float* __restrict__ x,
                       unsigned short* __restrict__ xb,
                       const float* __restrict__ Wq,
                       unsigned short* __restrict__ wqt,
                       const float* __restrict__ Wo,
                       unsigned short* __restrict__ wot) {
  __shared__ float tile[32][33];
  const int id = blockIdx.x;
  if (id < 4096) {
    const int i = id * 256 + threadIdx.x;      // exactly covers 1048576
    const float4* p = ((const float4*)x) + (size_t)i * 2;
    float4 a = p[0], b = p[1];
    ushort8_t v;
    v[0] = f2bf(a.x); v[1] = f2bf(a.y); v[2] = f2bf(a.z); v[3] = f2bf(a.w);
    v[4] = f2bf(b.x); v[5] = f2bf(b.y); v[6] = f2bf(b.z); v[7] = f2bf(b.w);
    ((ushort8_t*)xb)[i] = v;
    return;
  }
  const float* W;
  unsigned short* Wt;
  int N, bx, by;
  if (id < 7168) { W = Wq; Wt = wqt; N = 3072; bx = (id - 4096) % 96; by = (id - 4096) / 96; }
  else           { W = Wo; Wt = wot; N = 1024; bx = (id - 7168) % 32; by = (id - 7168) / 32; }
  const int K = 1024;
  const int c0 = bx * 32, r0 = by * 32;
  const int tx = threadIdx.x & 31, ty = threadIdx.x >> 5;
#pragma unroll
  for (int i = 0; i < 4; ++i) {
    int r = ty + i * 8;
    tile[r][tx] = W[(size_t)(r0 + r) * N + c0 + tx];
  }
  __syncthreads();
#pragma unroll
  for (int i = 0; i < 4; ++i) {
    int r = ty + i * 8;
    Wt[(size_t)(c0 + r) * K + r0 + tx] = f2bf(tile[tx][r]);
  }
}

// --------------------------------------------------------------- 128^2 GEMM
// A [M][1024] bf16, Bt [N][1024] bf16. EPI 0: QKV scatter (Q pre-scaled).
// EPI 1: fp32 out. XCD-aware swizzle (verified round 8). BK=64 via two
// 32-wide sub-steps per barrier pair (iterations 32 -> 16; verified round 13).
template <int EPI, int NBX>
__global__ __launch_bounds__(256, 2) void k_gemm(
    const unsigned short* __restrict__ A, const unsigned short* __restrict__ Bt,
    const float* __restrict__ bias, unsigned short* __restrict__ Qo,
    unsigned short* __restrict__ Ko, unsigned short* __restrict__ VTo,
    float* __restrict__ Out) {
  __shared__ unsigned short As[2][2][128 * 32];   // [buf][sub] 8 KB each
  __shared__ unsigned short Bs[2][2][128 * 32];
  const int tid = threadIdx.x;
  const int lane = tid & 63, wid = tid >> 6;
  const int wr = wid >> 1, wc = wid & 1;
  const int g = lane >> 4, r = lane & 15;
  const int lid = blockIdx.y * NBX + blockIdx.x;
  const int total = NBX * gridDim.y;
  const int id = (lid & 7) * (total >> 3) + (lid >> 3);
  const int m0 = (id / NBX) * 128, n0 = (id % NBX) * 128;

  // hoisted staging pointers: seg i*256+tid -> row=seg>>2, sl=seg&3
  const int row0 = tid >> 2, sl0 = tid & 3;        // i=0: rows 0..63
  const unsigned short* a0 = A + (size_t)(m0 + row0) * 1024 + sl0 * 8;
  const unsigned short* a1 = A + (size_t)(m0 + 64 + row0) * 1024 + sl0 * 8;
  const unsigned short* b0 = Bt + (size_t)(n0 + row0) * 1024 + sl0 * 8;
  const unsigned short* b1 = Bt + (size_t)(n0 + 64 + row0) * 1024 + sl0 * 8;
  char* adst = (char*)As + wid * 64 * 16;   // +4096 rows-half, +8192 sub, +16384 buf
  char* bdst = (char*)Bs + wid * 64 * 16;

  auto STAGE = [&](int buf) {  // stages one BK=64 K-step (both subs); advances
    const int bo = buf * 16384;
    gload_lds16(a0,      adst + bo);
    gload_lds16(a1,      adst + bo + 4096);
    gload_lds16(a0 + 32, adst + bo + 8192);
    gload_lds16(a1 + 32, adst + bo + 8192 + 4096);
    gload_lds16(b0,      bdst + bo);
    gload_lds16(b1,      bdst + bo + 4096);
    gload_lds16(b0 + 32, bdst + bo + 8192);
    gload_lds16(b1 + 32, bdst + bo + 8192 + 4096);
    a0 += 64; a1 += 64; b0 += 64; b1 += 64;
  };

  f32x4 zero4 = {0.f, 0.f, 0.f, 0.f};
  f32x4 acc[4][4];
#pragma unroll
  for (int mi = 0; mi < 4; ++mi)
#pragma unroll
    for (int ni = 0; ni < 4; ++ni) acc[mi][ni] = zero4;

  STAGE(0);
  asm volatile("s_waitcnt vmcnt(0)" ::: "memory");
  __builtin_amdgcn_s_barrier();

  for (int t = 0; t < 16; ++t) {
    const int cur = t & 1;
    if (t < 15) STAGE(cur ^ 1);        // issue next K-step's loads early
#pragma unroll
    for (int sub = 0; sub < 2; ++sub) {
      short8 af[4], bf[4];
#pragma unroll
      for (int mi = 0; mi < 4; ++mi)
        af[mi] = *(const short8*)&As[cur][sub][(wr * 64 + mi * 16 + r) * 32 + g * 8];
#pragma unroll
      for (int ni = 0; ni < 4; ++ni)
        bf[ni] = *(const short8*)&Bs[cur][sub][(wc * 64 + ni * 16 + r) * 32 + g * 8];
#pragma unroll
      for (int mi = 0; mi < 4; ++mi)
#pragma unroll
        for (int ni = 0; ni < 4; ++ni)
          acc[mi][ni] = __builtin_amdgcn_mfma_f32_16x16x32_bf16(
              af[mi], bf[ni], acc[mi][ni], 0, 0, 0);
    }
    asm volatile("s_waitcnt vmcnt(0)" ::: "memory");  // next-step loads landed
    __builtin_amdgcn_s_barrier();
  }

#pragma unroll
  for (int mi = 0; mi < 4; ++mi) {
#pragma unroll
    for (int ni = 0; ni < 4; ++ni) {
      const int n = n0 + wc * 64 + ni * 16 + r;
      const float bv = bias[n];
      const int mbase = m0 + wr * 64 + mi * 16 + g * 4;
      if (EPI == 0) {
        const int sec = n >> 10, e = n & 1023, h = e >> 6, dd = e & 63;
        const int b = mbase >> 11, t = mbase & 2047;
        if (sec == 2) {  // V transposed: [B,H,64,2048], 4 consecutive t packed
          ushort4_t pk;
#pragma unroll
          for (int j = 0; j < 4; ++j) pk[j] = f2bf(acc[mi][ni][j] + bv);
          *(ushort4_t*)&VTo[(((size_t)b * 16 + h) * 64 + dd) * 2048 + t] = pk;
        } else {
          unsigned short* dst = (sec == 0) ? Qo : Ko;
          const float scl = (sec == 0) ? QSCALE : 1.0f;  // fold softmax scale
#pragma unroll
          for (int j = 0; j < 4; ++j)
            dst[(((size_t)b * 16 + h) * 2048 + t + j) * 64 + dd] =
                f2bf((acc[mi][ni][j] + bv) * scl);
        }
      } else {
#pragma unroll
        for (int j = 0; j < 4; ++j)
          Out[(size_t)(mbase + j) * 1024 + n] = acc[mi][ni][j] + bv;
      }
    }
  }
}

// ------------------------------------------------------------ flash attention
// 1D grid 512, XCD-swizzled: xcd=id&7 owns bh in [xcd*8,+8) x 8 qblocks of
// 256 q-rows. 8 waves; wave owns 32 q-rows x ALL 64 keys. KV tile 64,
// double-buffered. REG-STAGED: coalesced global row loads -> ds_write to
// dual-conflict-free XOR layout -> lane-cyclic conflict-free fragment reads.
// Basis-free softmax; all-ones-MFMA row-sum. Same barrier structure as r14.
__global__ __launch_bounds__(512, 4) void k_attn(
    const unsigned short* __restrict__ Qg, const unsigned short* __restrict__ Kg,
    const unsigned short* __restrict__ VTg, const int* __restrict__ maskp,
    unsigned short* __restrict__ ctx) {
  __shared__ unsigned short Ks[2 * 4096];     // [buf][512 slots x 16B]
  __shared__ unsigned short Vs[2 * 4096];
  const int tid = threadIdx.x, lane = tid & 63, wid = tid >> 6;
  const int q = lane & 31, hi = lane >> 5;
  const int id = blockIdx.x;
  const int slot = id >> 3;
  const int bh = (id & 7) * 8 + (slot >> 3);
  const int b = bh >> 4, h = bh & 15;
  const int q0 = (slot & 7) * 256 + wid * 32;
  const int qr = q0 + q;

  const unsigned short* Qb = Qg + (size_t)bh * SEQ * 64;
  const unsigned short* Kb = Kg + (size_t)bh * SEQ * 64;
  const unsigned short* Vb = VTg + (size_t)bh * 64 * SEQ;
  const int* mb = maskp + b * SEQ;

  // reg-staging geometry: thread t -> row t>>3, chunk c=t&7 (coalesced rows)
  const int srow = tid >> 3, sc = tid & 7;
  const unsigned short* kp = Kb + srow * 64 + sc * 8;            // +4096/tile
  const unsigned short* vp = Vb + (size_t)srow * SEQ + sc * 8;   // +64/tile
  // phys slot = [(c>>1)*128 + (row>>5)*64 + (c&1)*32 + (row&31)] ^ (c&7)
  const int pslot = ((sc >> 1) * 128 + (srow >> 5) * 64 + (sc & 1) * 32 +
                     (srow & 31)) ^ (sc & 7);
  char* kw = (char*)Ks + pslot * 16;          // + buf*8192
  char* vw = (char*)Vs + pslot * 16;

  // Q fragments (B-operand of S^T mfma): lane holds Q[qr][ds*16 + hi*8 + 0..7]
  short8 qf[4];
#pragma unroll
  for (int ds = 0; ds < 4; ++ds)
    qf[ds] = *(const short8*)&Qb[(size_t)qr * 64 + ds * 16 + hi * 8];

  // all-ones bf16 A-fragment (constant matrix => fragment-layout-proof)
  short8 onesf;
#pragma unroll
  for (int j = 0; j < 8; ++j) onesf[j] = (short)0x3F80;

  f32x16 z16 = {0.f,0.f,0.f,0.f,0.f,0.f,0.f,0.f,0.f,0.f,0.f,0.f,0.f,0.f,0.f,0.f};
  f32x16 o0 = z16, o1 = z16;   // O^T[dd][q]: dd = (i&3)+8*(i>>2)+4*hi (+32)
  f32x16 osum = z16;           // every component = sum_k P[q][k] (all rows =)
  const int kb4 = hi * 4;

  // prologue: stage tile 0 through registers
  {
    short8 kreg = *(const short8*)kp;  kp += 4096;
    short8 vreg = *(const short8*)vp;  vp += 64;
    *(short8*)kw = kreg;
    *(short8*)vw = vreg;
  }
  const int* mptr = mb + lane;
  int mv = mptr[0];
  mptr += 64;
  __syncthreads();

  for (int t = 0; t < 32; ++t) {
    const int cur = t & 1;
    short8 kreg, vreg;
    int mvn = 1;
    if (t < 31) {                          // issue next tile's loads early
      kreg = *(const short8*)kp;  kp += 4096;
      vreg = *(const short8*)vp;  vp += 64;
      mvn = mptr[0];
      mptr += 64;
    }
    const unsigned long long bits = __ballot(mv != 0);
    mv = mvn;

    // S^T = K Q^T : lane holds S^T[key][q=lane&31], keys (i&3)+8*(i>>2)+4*hi
    const char* KsB = (const char*)Ks + cur * 8192;
    const char* VsB = (const char*)Vs + cur * 8192;
    f32x16 c0 = z16, c1 = z16;
    __builtin_amdgcn_s_setprio(1);
#pragma unroll
    for (int ds = 0; ds < 4; ++ds) {
      const int ko = (lane ^ ((ds * 2 + hi) & 7)) * 16 + ds * 2048;
      short8 ka0 = *(const short8*)(KsB + ko);
      short8 ka1 = *(const short8*)(KsB + ko + 1024);
      c0 = __builtin_amdgcn_mfma_f32_32x32x16_bf16(ka0, qf[ds], c0, 0, 0, 0);
      c1 = __builtin_amdgcn_mfma_f32_32x32x16_bf16(ka1, qf[ds], c1, 0, 0, 0);
    }
    __builtin_amdgcn_s_setprio(0);

    // P = exp2(S') directly — scale folded into Q, basis-free (cancels)
#pragma unroll
    for (int i = 0; i < 16; ++i) {
      c0[i] = exp2_raw(c0[i]);
      c1[i] = exp2_raw(c1[i]);
    }
    if (bits != ~0ull) {  // wave-uniform: only when mask has zeros
#pragma unroll
      for (int i = 0; i < 16; ++i) {
        const int k0 = (i & 3) + 8 * (i >> 2) + kb4;
        if (!((bits >> k0) & 1)) c0[i] = 0.f;
        if (!((bits >> (k0 + 32)) & 1)) c1[i] = 0.f;
      }
    }

    // P -> bf16 PV fragments, in-register (cvt_pk + permlane32_swap)
    short8 pf[4];
#pragma unroll
    for (int sub = 0; sub < 2; ++sub) {
      uint32_t w[8];
#pragma unroll
      for (int j = 0; j < 8; ++j)
        w[j] = sub ? cvtpk(c1[2 * j], c1[2 * j + 1])
                   : cvtpk(c0[2 * j], c0[2 * j + 1]);
      asm("v_permlane32_swap_b32 %0, %1" : "+v"(w[0]), "+v"(w[2]));
      asm("v_permlane32_swap_b32 %0, %1" : "+v"(w[1]), "+v"(w[3]));
      asm("v_permlane32_swap_b32 %0, %1" : "+v"(w[4]), "+v"(w[6]));
      asm("v_permlane32_swap_b32 %0, %1" : "+v"(w[5]), "+v"(w[7]));
      union { uint32_t u[4]; short8 s; } ua, ub;
      ua.u[0] = w[0]; ua.u[1] = w[1]; ua.u[2] = w[2]; ua.u[3] = w[3];
      ub.u[0] = w[4]; ub.u[1] = w[5]; ub.u[2] = w[6]; ub.u[3] = w[7];
      pf[sub * 2] = ua.s;
      pf[sub * 2 + 1] = ub.s;
    }

    // O^T += V^T P^T ; row-sum += 1 * P^T (all-ones A => each row = sum_k P)
    __builtin_amdgcn_s_setprio(1);
#pragma unroll
    for (int ks = 0; ks < 4; ++ks) {
      const int vo = (lane ^ ((ks * 2 + hi) & 7)) * 16 + ks * 2048;
      short8 va0 = *(const short8*)(VsB + vo);
      short8 va1 = *(const short8*)(VsB + vo + 1024);
      o0 = __builtin_amdgcn_mfma_f32_32x32x16_bf16(va0, pf[ks], o0, 0, 0, 0);
      o1 = __builtin_amdgcn_mfma_f32_32x32x16_bf16(va1, pf[ks], o1, 0, 0, 0);
      osum = __builtin_amdgcn_mfma_f32_32x32x16_bf16(onesf, pf[ks], osum,
                                                     0, 0, 0);
    }
    __builtin_amdgcn_s_setprio(0);

    if (t < 31) {                          // late write into the other buffer
      const int bo = (cur ^ 1) * 8192;
      *(short8*)(kw + bo) = kreg;
      *(short8*)(vw + bo) = vreg;
    }
    __syncthreads();
  }

  // ctx [B,T,1024] bf16: lane writes its query row qr, dd groups of 4
  const float inv = 1.f / osum[0];
#pragma unroll
  for (int ns = 0; ns < 2; ++ns) {
#pragma unroll
    for (int g_ = 0; g_ < 4; ++g_) {
      ushort4_t v4;
#pragma unroll
      for (int e = 0; e < 4; ++e) {
        const float val = (ns ? o1[g_ * 4 + e] : o0[g_ * 4 + e]) * inv;
        v4[e] = f2bf(val);
      }
      *(ushort4_t*)&ctx[((size_t)b * SEQ + qr) * 1024 + h * 64 + ns * 32 +
                        g_ * 8 + hi * 4] = v4;
    }
  }
}

// ---------------------------------------------------------------------------
extern "C" void kernel_launch(void* const* d_in, const int* in_sizes, int n_in,
                              void* d_out, int out_size, void* d_ws,
                              size_t ws_size, hipStream_t stream) {
  const float* x = (const float*)d_in[0];
  const int* mask = (const int*)d_in[1];
  const float* Wqkv = (const float*)d_in[2];
  const float* bqkv = (const float*)d_in[3];
  const float* Wout = (const float*)d_in[4];
  const float* bout = (const float*)d_in[5];
  float* out = (float*)d_out;

  unsigned short* ws = (unsigned short*)d_ws;
  unsigned short* xb = ws;                       // 8388608 (reused as ctx)
  unsigned short* wqt = ws + 8388608;            // 3145728
  unsigned short* wot = ws + 11534336;           // 1048576
  unsigned short* Q = ws + 12582912;             // 8388608
  unsigned short* K = ws + 20971520;             // 8388608
  unsigned short* VT = ws + 29360128;            // 8388608
  unsigned short* ctx = xb;

  k_prep<<<8192, 256, 0, stream>>>(x, xb, Wqkv, wqt, Wout, wot);
  k_gemm<0, 24><<<dim3(24, 64), 256, 0, stream>>>(xb, wqt, bqkv, Q, K, VT,
                                                  nullptr);
  k_attn<<<512, 512, 0, stream>>>(Q, K, VT, mask, ctx);
  k_gemm<1, 8><<<dim3(8, 64), 256, 0, stream>>>(ctx, wot, bout, nullptr,
                                                nullptr, nullptr, out);
}

// Round 19
// 188.929 us; speedup vs baseline: 1.3175x; 1.2661x over previous
//
#include <hip/hip_runtime.h>
#include <hip/hip_bf16.h>
#include <stdint.h>

// ---------------------------------------------------------------------------
// MultiHeadAttention forward, MI355X bf16-MFMA implementation.
//   x[4,2048,1024] @ W_qkv[1024,3072] + b  -> Q,K -> [B,H,T,64], V -> [B,H,64,T]
//   flash attention per (b,h), T=2048, d=64 -> ctx [B,T,1024] bf16
//   ctx @ W_out + b_out -> out fp32 [4,2048,1024]
// Round 19: r18's reg-staged dual-conflict-free attn with the SCRATCH SPILL
// fixed. r18 evidence: SQ_LDS_BANK_CONFLICT=0 (layout correct) but WRITE_SIZE
// 448MB = kreg/vreg spilled every iter (launch_bounds(512,4) -> 64-VGPR cap;
// conditional defs + whole-body live range). Fix: (1) loads UNCONDITIONAL with
// clamped pointer advance (t<30); (2) ds_write moved right after QK^T so the
// staged regs live across only 8 MFMAs (QK^T also hides the L2 latency).
// Same one-barrier-per-iteration dbuf proof as r18. GEMMs/prep = r16 verified.
// ---------------------------------------------------------------------------

typedef __attribute__((ext_vector_type(8))) short short8;
typedef __attribute__((ext_vector_type(4))) float f32x4;
typedef __attribute__((ext_vector_type(16))) float f32x16;
typedef __attribute__((ext_vector_type(4))) unsigned short ushort4_t;
typedef __attribute__((ext_vector_type(8))) unsigned short ushort8_t;

#define SEQ 2048
#define EDIM 1024
// 0.125 * log2(e): folded into Q so scores arrive in the log2 domain
#define QSCALE 0.18033688011112042f

__device__ __forceinline__ unsigned short f2bf(float x) {
  union { float f; uint32_t u; } v; v.f = x;
  uint32_t r = v.u + 0x7fffu + ((v.u >> 16) & 1u);
  return (unsigned short)(r >> 16);
}

__device__ __forceinline__ uint32_t cvtpk(float lo, float hi) {
  uint32_t r;
  asm("v_cvt_pk_bf16_f32 %0, %1, %2" : "=v"(r) : "v"(lo), "v"(hi));
  return r;
}

__device__ __forceinline__ float exp2_raw(float x) {
  float r;
  asm("v_exp_f32 %0, %1" : "=v"(r) : "v"(x));
  return r;
}

__device__ __forceinline__ void gload_lds16(const void* g, void* l) {
  typedef __attribute__((address_space(1))) const unsigned int gu32;
  typedef __attribute__((address_space(3))) unsigned int lu32;
  __builtin_amdgcn_global_load_lds((gu32*)g, (lu32*)l, 16, 0, 0);
}

// ------------------------- merged prep: fp32->bf16 cvt + 2 weight transposes
// grid 8192: [0,4096) cvt x; [4096,7168) Wqkv^T; [7168,8192) Wout^T
__global__ void k_prep(const float* __restrict__ x,
                       unsigned short* __restrict__ xb,
                       const float* __restrict__ Wq,
                       unsigned short* __restrict__ wqt,
                       const float* __restrict__ Wo,
                       unsigned short* __restrict__ wot) {
  __shared__ float tile[32][33];
  const int id = blockIdx.x;
  if (id < 4096) {
    const int i = id * 256 + threadIdx.x;      // exactly covers 1048576
    const float4* p = ((const float4*)x) + (size_t)i * 2;
    float4 a = p[0], b = p[1];
    ushort8_t v;
    v[0] = f2bf(a.x); v[1] = f2bf(a.y); v[2] = f2bf(a.z); v[3] = f2bf(a.w);
    v[4] = f2bf(b.x); v[5] = f2bf(b.y); v[6] = f2bf(b.z); v[7] = f2bf(b.w);
    ((ushort8_t*)xb)[i] = v;
    return;
  }
  const float* W;
  unsigned short* Wt;
  int N, bx, by;
  if (id < 7168) { W = Wq; Wt = wqt; N = 3072; bx = (id - 4096) % 96; by = (id - 4096) / 96; }
  else           { W = Wo; Wt = wot; N = 1024; bx = (id - 7168) % 32; by = (id - 7168) / 32; }
  const int K = 1024;
  const int c0 = bx * 32, r0 = by * 32;
  const int tx = threadIdx.x & 31, ty = threadIdx.x >> 5;
#pragma unroll
  for (int i = 0; i < 4; ++i) {
    int r = ty + i * 8;
    tile[r][tx] = W[(size_t)(r0 + r) * N + c0 + tx];
  }
  __syncthreads();
#pragma unroll
  for (int i = 0; i < 4; ++i) {
    int r = ty + i * 8;
    Wt[(size_t)(c0 + r) * K + r0 + tx] = f2bf(tile[tx][r]);
  }
}

// --------------------------------------------------------------- 128^2 GEMM
// A [M][1024] bf16, Bt [N][1024] bf16. EPI 0: QKV scatter (Q pre-scaled).
// EPI 1: fp32 out. XCD-aware swizzle (verified round 8). BK=64 via two
// 32-wide sub-steps per barrier pair (iterations 32 -> 16; verified round 13).
template <int EPI, int NBX>
__global__ __launch_bounds__(256, 2) void k_gemm(
    const unsigned short* __restrict__ A, const unsigned short* __restrict__ Bt,
    const float* __restrict__ bias, unsigned short* __restrict__ Qo,
    unsigned short* __restrict__ Ko, unsigned short* __restrict__ VTo,
    float* __restrict__ Out) {
  __shared__ unsigned short As[2][2][128 * 32];   // [buf][sub] 8 KB each
  __shared__ unsigned short Bs[2][2][128 * 32];
  const int tid = threadIdx.x;
  const int lane = tid & 63, wid = tid >> 6;
  const int wr = wid >> 1, wc = wid & 1;
  const int g = lane >> 4, r = lane & 15;
  const int lid = blockIdx.y * NBX + blockIdx.x;
  const int total = NBX * gridDim.y;
  const int id = (lid & 7) * (total >> 3) + (lid >> 3);
  const int m0 = (id / NBX) * 128, n0 = (id % NBX) * 128;

  // hoisted staging pointers: seg i*256+tid -> row=seg>>2, sl=seg&3
  const int row0 = tid >> 2, sl0 = tid & 3;        // i=0: rows 0..63
  const unsigned short* a0 = A + (size_t)(m0 + row0) * 1024 + sl0 * 8;
  const unsigned short* a1 = A + (size_t)(m0 + 64 + row0) * 1024 + sl0 * 8;
  const unsigned short* b0 = Bt + (size_t)(n0 + row0) * 1024 + sl0 * 8;
  const unsigned short* b1 = Bt + (size_t)(n0 + 64 + row0) * 1024 + sl0 * 8;
  char* adst = (char*)As + wid * 64 * 16;   // +4096 rows-half, +8192 sub, +16384 buf
  char* bdst = (char*)Bs + wid * 64 * 16;

  auto STAGE = [&](int buf) {  // stages one BK=64 K-step (both subs); advances
    const int bo = buf * 16384;
    gload_lds16(a0,      adst + bo);
    gload_lds16(a1,      adst + bo + 4096);
    gload_lds16(a0 + 32, adst + bo + 8192);
    gload_lds16(a1 + 32, adst + bo + 8192 + 4096);
    gload_lds16(b0,      bdst + bo);
    gload_lds16(b1,      bdst + bo + 4096);
    gload_lds16(b0 + 32, bdst + bo + 8192);
    gload_lds16(b1 + 32, bdst + bo + 8192 + 4096);
    a0 += 64; a1 += 64; b0 += 64; b1 += 64;
  };

  f32x4 zero4 = {0.f, 0.f, 0.f, 0.f};
  f32x4 acc[4][4];
#pragma unroll
  for (int mi = 0; mi < 4; ++mi)
#pragma unroll
    for (int ni = 0; ni < 4; ++ni) acc[mi][ni] = zero4;

  STAGE(0);
  asm volatile("s_waitcnt vmcnt(0)" ::: "memory");
  __builtin_amdgcn_s_barrier();

  for (int t = 0; t < 16; ++t) {
    const int cur = t & 1;
    if (t < 15) STAGE(cur ^ 1);        // issue next K-step's loads early
#pragma unroll
    for (int sub = 0; sub < 2; ++sub) {
      short8 af[4], bf[4];
#pragma unroll
      for (int mi = 0; mi < 4; ++mi)
        af[mi] = *(const short8*)&As[cur][sub][(wr * 64 + mi * 16 + r) * 32 + g * 8];
#pragma unroll
      for (int ni = 0; ni < 4; ++ni)
        bf[ni] = *(const short8*)&Bs[cur][sub][(wc * 64 + ni * 16 + r) * 32 + g * 8];
#pragma unroll
      for (int mi = 0; mi < 4; ++mi)
#pragma unroll
        for (int ni = 0; ni < 4; ++ni)
          acc[mi][ni] = __builtin_amdgcn_mfma_f32_16x16x32_bf16(
              af[mi], bf[ni], acc[mi][ni], 0, 0, 0);
    }
    asm volatile("s_waitcnt vmcnt(0)" ::: "memory");  // next-step loads landed
    __builtin_amdgcn_s_barrier();
  }

#pragma unroll
  for (int mi = 0; mi < 4; ++mi) {
#pragma unroll
    for (int ni = 0; ni < 4; ++ni) {
      const int n = n0 + wc * 64 + ni * 16 + r;
      const float bv = bias[n];
      const int mbase = m0 + wr * 64 + mi * 16 + g * 4;
      if (EPI == 0) {
        const int sec = n >> 10, e = n & 1023, h = e >> 6, dd = e & 63;
        const int b = mbase >> 11, t = mbase & 2047;
        if (sec == 2) {  // V transposed: [B,H,64,2048], 4 consecutive t packed
          ushort4_t pk;
#pragma unroll
          for (int j = 0; j < 4; ++j) pk[j] = f2bf(acc[mi][ni][j] + bv);
          *(ushort4_t*)&VTo[(((size_t)b * 16 + h) * 64 + dd) * 2048 + t] = pk;
        } else {
          unsigned short* dst = (sec == 0) ? Qo : Ko;
          const float scl = (sec == 0) ? QSCALE : 1.0f;  // fold softmax scale
#pragma unroll
          for (int j = 0; j < 4; ++j)
            dst[(((size_t)b * 16 + h) * 2048 + t + j) * 64 + dd] =
                f2bf((acc[mi][ni][j] + bv) * scl);
        }
      } else {
#pragma unroll
        for (int j = 0; j < 4; ++j)
          Out[(size_t)(mbase + j) * 1024 + n] = acc[mi][ni][j] + bv;
      }
    }
  }
}

// ------------------------------------------------------------ flash attention
// 1D grid 512, XCD-swizzled. 8 waves; wave owns 32 q-rows x ALL 64 keys.
// KV tile 64, double-buffered. REG-STAGED (coalesced rows) -> ds_write to
// dual-conflict-free XOR layout RIGHT AFTER QK^T (short live range, no spill)
// -> lane-cyclic conflict-free fragment reads. Loads unconditional, pointer
// advance clamped at t<30 (t=31 reloads tile 31, discarded).
// Basis-free softmax; all-ones-MFMA row-sum.
__global__ __launch_bounds__(512, 4) void k_attn(
    const unsigned short* __restrict__ Qg, const unsigned short* __restrict__ Kg,
    const unsigned short* __restrict__ VTg, const int* __restrict__ maskp,
    unsigned short* __restrict__ ctx) {
  __shared__ unsigned short Ks[2 * 4096];     // [buf][512 slots x 16B]
  __shared__ unsigned short Vs[2 * 4096];
  const int tid = threadIdx.x, lane = tid & 63, wid = tid >> 6;
  const int q = lane & 31, hi = lane >> 5;
  const int id = blockIdx.x;
  const int slot = id >> 3;
  const int bh = (id & 7) * 8 + (slot >> 3);
  const int b = bh >> 4, h = bh & 15;
  const int q0 = (slot & 7) * 256 + wid * 32;
  const int qr = q0 + q;

  const unsigned short* Qb = Qg + (size_t)bh * SEQ * 64;
  const unsigned short* Kb = Kg + (size_t)bh * SEQ * 64;
  const unsigned short* Vb = VTg + (size_t)bh * 64 * SEQ;
  const int* mb = maskp + b * SEQ;

  // reg-staging geometry: thread t -> row t>>3, chunk c=t&7 (coalesced rows)
  const int srow = tid >> 3, sc = tid & 7;
  const unsigned short* kp = Kb + srow * 64 + sc * 8;            // +4096/tile
  const unsigned short* vp = Vb + (size_t)srow * SEQ + sc * 8;   // +64/tile
  // phys slot = [(c>>1)*128 + (row>>5)*64 + (c&1)*32 + (row&31)] ^ (c&7)
  const int pslot = ((sc >> 1) * 128 + (srow >> 5) * 64 + (sc & 1) * 32 +
                     (srow & 31)) ^ (sc & 7);
  char* kw = (char*)Ks + pslot * 16;          // + buf*8192
  char* vw = (char*)Vs + pslot * 16;

  // Q fragments (B-operand of S^T mfma): lane holds Q[qr][ds*16 + hi*8 + 0..7]
  short8 qf[4];
#pragma unroll
  for (int ds = 0; ds < 4; ++ds)
    qf[ds] = *(const short8*)&Qb[(size_t)qr * 64 + ds * 16 + hi * 8];

  // all-ones bf16 A-fragment (constant matrix => fragment-layout-proof)
  short8 onesf;
#pragma unroll
  for (int j = 0; j < 8; ++j) onesf[j] = (short)0x3F80;

  f32x16 z16 = {0.f,0.f,0.f,0.f,0.f,0.f,0.f,0.f,0.f,0.f,0.f,0.f,0.f,0.f,0.f,0.f};
  f32x16 o0 = z16, o1 = z16;   // O^T[dd][q]: dd = (i&3)+8*(i>>2)+4*hi (+32)
  f32x16 osum = z16;           // every component = sum_k P[q][k] (all rows =)
  const int kb4 = hi * 4;

  // prologue: stage tile 0 through registers into buf 0
  {
    short8 kreg = *(const short8*)kp;  kp += 4096;
    short8 vreg = *(const short8*)vp;  vp += 64;
    *(short8*)kw = kreg;
    *(short8*)vw = vreg;
  }
  const int* mptr = mb + lane;
  int mv = mptr[0];
  mptr += 64;
  __syncthreads();

  for (int t = 0; t < 32; ++t) {
    const int cur = t & 1;
    // unconditional loads of tile t+1 (t=31 reloads tile 31 -> discarded)
    short8 kreg = *(const short8*)kp;
    short8 vreg = *(const short8*)vp;
    const int mvn = mptr[0];
    if (t < 30) { kp += 4096; vp += 64; mptr += 64; }
    const unsigned long long bits = __ballot(mv != 0);
    mv = mvn;

    // S^T = K Q^T : lane holds S^T[key][q=lane&31], keys (i&3)+8*(i>>2)+4*hi
    const char* KsB = (const char*)Ks + cur * 8192;
    const char* VsB = (const char*)Vs + cur * 8192;
    f32x16 c0 = z16, c1 = z16;
    __builtin_amdgcn_s_setprio(1);
#pragma unroll
    for (int ds = 0; ds < 4; ++ds) {
      const int ko = (lane ^ ((ds * 2 + hi) & 7)) * 16 + ds * 2048;
      short8 ka0 = *(const short8*)(KsB + ko);
      short8 ka1 = *(const short8*)(KsB + ko + 1024);
      c0 = __builtin_amdgcn_mfma_f32_32x32x16_bf16(ka0, qf[ds], c0, 0, 0, 0);
      c1 = __builtin_amdgcn_mfma_f32_32x32x16_bf16(ka1, qf[ds], c1, 0, 0, 0);
    }
    __builtin_amdgcn_s_setprio(0);

    // write tile t+1 into buf cur^1 NOW (short kreg/vreg live range; QK^T
    // above hid the L2 latency; barrier-separated from all cur^1 readers)
    {
      const int bo = (cur ^ 1) * 8192;
      *(short8*)(kw + bo) = kreg;
      *(short8*)(vw + bo) = vreg;
    }

    // P = exp2(S') directly — scale folded into Q, basis-free (cancels)
#pragma unroll
    for (int i = 0; i < 16; ++i) {
      c0[i] = exp2_raw(c0[i]);
      c1[i] = exp2_raw(c1[i]);
    }
    if (bits != ~0ull) {  // wave-uniform: only when mask has zeros
#pragma unroll
      for (int i = 0; i < 16; ++i) {
        const int k0 = (i & 3) + 8 * (i >> 2) + kb4;
        if (!((bits >> k0) & 1)) c0[i] = 0.f;
        if (!((bits >> (k0 + 32)) & 1)) c1[i] = 0.f;
      }
    }

    // P -> bf16 PV fragments, in-register (cvt_pk + permlane32_swap)
    short8 pf[4];
#pragma unroll
    for (int sub = 0; sub < 2; ++sub) {
      uint32_t w[8];
#pragma unroll
      for (int j = 0; j < 8; ++j)
        w[j] = sub ? cvtpk(c1[2 * j], c1[2 * j + 1])
                   : cvtpk(c0[2 * j], c0[2 * j + 1]);
      asm("v_permlane32_swap_b32 %0, %1" : "+v"(w[0]), "+v"(w[2]));
      asm("v_permlane32_swap_b32 %0, %1" : "+v"(w[1]), "+v"(w[3]));
      asm("v_permlane32_swap_b32 %0, %1" : "+v"(w[4]), "+v"(w[6]));
      asm("v_permlane32_swap_b32 %0, %1" : "+v"(w[5]), "+v"(w[7]));
      union { uint32_t u[4]; short8 s; } ua, ub;
      ua.u[0] = w[0]; ua.u[1] = w[1]; ua.u[2] = w[2]; ua.u[3] = w[3];
      ub.u[0] = w[4]; ub.u[1] = w[5]; ub.u[2] = w[6]; ub.u[3] = w[7];
      pf[sub * 2] = ua.s;
      pf[sub * 2 + 1] = ub.s;
    }

    // O^T += V^T P^T ; row-sum += 1 * P^T (all-ones A => each row = sum_k P)
    __builtin_amdgcn_s_setprio(1);
#pragma unroll
    for (int ks = 0; ks < 4; ++ks) {
      const int vo = (lane ^ ((ks * 2 + hi) & 7)) * 16 + ks * 2048;
      short8 va0 = *(const short8*)(VsB + vo);
      short8 va1 = *(const short8*)(VsB + vo + 1024);
      o0 = __builtin_amdgcn_mfma_f32_32x32x16_bf16(va0, pf[ks], o0, 0, 0, 0);
      o1 = __builtin_amdgcn_mfma_f32_32x32x16_bf16(va1, pf[ks], o1, 0, 0, 0);
      osum = __builtin_amdgcn_mfma_f32_32x32x16_bf16(onesf, pf[ks], osum,
                                                     0, 0, 0);
    }
    __builtin_amdgcn_s_setprio(0);

    __syncthreads();
  }

  // ctx [B,T,1024] bf16: lane writes its query row qr, dd groups of 4
  const float inv = 1.f / osum[0];
#pragma unroll
  for (int ns = 0; ns < 2; ++ns) {
#pragma unroll
    for (int g_ = 0; g_ < 4; ++g_) {
      ushort4_t v4;
#pragma unroll
      for (int e = 0; e < 4; ++e) {
        const float val = (ns ? o1[g_ * 4 + e] : o0[g_ * 4 + e]) * inv;
        v4[e] = f2bf(val);
      }
      *(ushort4_t*)&ctx[((size_t)b * SEQ + qr) * 1024 + h * 64 + ns * 32 +
                        g_ * 8 + hi * 4] = v4;
    }
  }
}

// ---------------------------------------------------------------------------
extern "C" void kernel_launch(void* const* d_in, const int* in_sizes, int n_in,
                              void* d_out, int out_size, void* d_ws,
                              size_t ws_size, hipStream_t stream) {
  const float* x = (const float*)d_in[0];
  const int* mask = (const int*)d_in[1];
  const float* Wqkv = (const float*)d_in[2];
  const float* bqkv = (const float*)d_in[3];
  const float* Wout = (const float*)d_in[4];
  const float* bout = (const float*)d_in[5];
  float* out = (float*)d_out;

  unsigned short* ws = (unsigned short*)d_ws;
  unsigned short* xb = ws;                       // 8388608 (reused as ctx)
  unsigned short* wqt = ws + 8388608;            // 3145728
  unsigned short* wot = ws + 11534336;           // 1048576
  unsigned short* Q = ws + 12582912;             // 8388608
  unsigned short* K = ws + 20971520;             // 8388608
  unsigned short* VT = ws + 29360128;            // 8388608
  unsigned short* ctx = xb;

  k_prep<<<8192, 256, 0, stream>>>(x, xb, Wqkv, wqt, Wout, wot);
  k_gemm<0, 24><<<dim3(24, 64), 256, 0, stream>>>(xb, wqt, bqkv, Q, K, VT,
                                                  nullptr);
  k_attn<<<512, 512, 0, stream>>>(Q, K, VT, mask, ctx);
  k_gemm<1, 8><<<dim3(8, 64), 256, 0, stream>>>(ctx, wot, bout, nullptr,
                                                nullptr, nullptr, out);
}

// Round 20
// 184.298 us; speedup vs baseline: 1.3506x; 1.0251x over previous
//
#include <hip/hip_runtime.h>
#include <hip/hip_bf16.h>
#include <stdint.h>

// ---------------------------------------------------------------------------
// MultiHeadAttention forward, MI355X bf16-MFMA implementation.
//   x[4,2048,1024] @ W_qkv[1024,3072] + b  -> Q,K -> [B,H,T,64], V -> [B,H,64,T]
//   flash attention per (b,h), T=2048, d=64 -> ctx [B,T,1024] bf16
//   ctx @ W_out + b_out -> out fp32 [4,2048,1024]
// Round 20: attn barrier-convoy reduction on the r19-verified structure:
//  (1) launch_bounds(512,4)->(512,2): occupancy is GRID-limited at 2 blocks/CU
//      (4 waves/SIMD), so the 64-VGPR cap bought nothing — 128-VGPR budget
//      removes all spill pressure (r18's failure mode).
//  (2) KVBLK=128 as two 64-key sub-tiles per barrier (16 iterations, barriers
//      halved). Inner compute = r19's verified 64-key block, inlined twice
//      with compile-time slab offsets. LDS 64KB -> still 2 blocks/CU.
//      Staged regs written right after QK-A into buf cur^1 (safe after the
//      prior barrier; same dbuf proof as r18/19).
// GEMMs (BK=64, r13) and prep (r9) unchanged.
// ---------------------------------------------------------------------------

typedef __attribute__((ext_vector_type(8))) short short8;
typedef __attribute__((ext_vector_type(4))) float f32x4;
typedef __attribute__((ext_vector_type(16))) float f32x16;
typedef __attribute__((ext_vector_type(4))) unsigned short ushort4_t;
typedef __attribute__((ext_vector_type(8))) unsigned short ushort8_t;

#define SEQ 2048
#define EDIM 1024
// 0.125 * log2(e): folded into Q so scores arrive in the log2 domain
#define QSCALE 0.18033688011112042f

__device__ __forceinline__ unsigned short f2bf(float x) {
  union { float f; uint32_t u; } v; v.f = x;
  uint32_t r = v.u + 0x7fffu + ((v.u >> 16) & 1u);
  return (unsigned short)(r >> 16);
}

__device__ __forceinline__ uint32_t cvtpk(float lo, float hi) {
  uint32_t r;
  asm("v_cvt_pk_bf16_f32 %0, %1, %2" : "=v"(r) : "v"(lo), "v"(hi));
  return r;
}

__device__ __forceinline__ float exp2_raw(float x) {
  float r;
  asm("v_exp_f32 %0, %1" : "=v"(r) : "v"(x));
  return r;
}

__device__ __forceinline__ void gload_lds16(const void* g, void* l) {
  typedef __attribute__((address_space(1))) const unsigned int gu32;
  typedef __attribute__((address_space(3))) unsigned int lu32;
  __builtin_amdgcn_global_load_lds((gu32*)g, (lu32*)l, 16, 0, 0);
}

// ------------------------- merged prep: fp32->bf16 cvt + 2 weight transposes
// grid 8192: [0,4096) cvt x; [4096,7168) Wqkv^T; [7168,8192) Wout^T
__global__ void k_prep(const float* __restrict__ x,
                       unsigned short* __restrict__ xb,
                       const float* __restrict__ Wq,
                       unsigned short* __restrict__ wqt,
                       const float* __restrict__ Wo,
                       unsigned short* __restrict__ wot) {
  __shared__ float tile[32][33];
  const int id = blockIdx.x;
  if (id < 4096) {
    const int i = id * 256 + threadIdx.x;      // exactly covers 1048576
    const float4* p = ((const float4*)x) + (size_t)i * 2;
    float4 a = p[0], b = p[1];
    ushort8_t v;
    v[0] = f2bf(a.x); v[1] = f2bf(a.y); v[2] = f2bf(a.z); v[3] = f2bf(a.w);
    v[4] = f2bf(b.x); v[5] = f2bf(b.y); v[6] = f2bf(b.z); v[7] = f2bf(b.w);
    ((ushort8_t*)xb)[i] = v;
    return;
  }
  const float* W;
  unsigned short* Wt;
  int N, bx, by;
  if (id < 7168) { W = Wq; Wt = wqt; N = 3072; bx = (id - 4096) % 96; by = (id - 4096) / 96; }
  else           { W = Wo; Wt = wot; N = 1024; bx = (id - 7168) % 32; by = (id - 7168) / 32; }
  const int K = 1024;
  const int c0 = bx * 32, r0 = by * 32;
  const int tx = threadIdx.x & 31, ty = threadIdx.x >> 5;
#pragma unroll
  for (int i = 0; i < 4; ++i) {
    int r = ty + i * 8;
    tile[r][tx] = W[(size_t)(r0 + r) * N + c0 + tx];
  }
  __syncthreads();
#pragma unroll
  for (int i = 0; i < 4; ++i) {
    int r = ty + i * 8;
    Wt[(size_t)(c0 + r) * K + r0 + tx] = f2bf(tile[tx][r]);
  }
}

// --------------------------------------------------------------- 128^2 GEMM
// A [M][1024] bf16, Bt [N][1024] bf16. EPI 0: QKV scatter (Q pre-scaled).
// EPI 1: fp32 out. XCD-aware swizzle (verified round 8). BK=64 via two
// 32-wide sub-steps per barrier pair (iterations 32 -> 16; verified round 13).
template <int EPI, int NBX>
__global__ __launch_bounds__(256, 2) void k_gemm(
    const unsigned short* __restrict__ A, const unsigned short* __restrict__ Bt,
    const float* __restrict__ bias, unsigned short* __restrict__ Qo,
    unsigned short* __restrict__ Ko, unsigned short* __restrict__ VTo,
    float* __restrict__ Out) {
  __shared__ unsigned short As[2][2][128 * 32];   // [buf][sub] 8 KB each
  __shared__ unsigned short Bs[2][2][128 * 32];
  const int tid = threadIdx.x;
  const int lane = tid & 63, wid = tid >> 6;
  const int wr = wid >> 1, wc = wid & 1;
  const int g = lane >> 4, r = lane & 15;
  const int lid = blockIdx.y * NBX + blockIdx.x;
  const int total = NBX * gridDim.y;
  const int id = (lid & 7) * (total >> 3) + (lid >> 3);
  const int m0 = (id / NBX) * 128, n0 = (id % NBX) * 128;

  // hoisted staging pointers: seg i*256+tid -> row=seg>>2, sl=seg&3
  const int row0 = tid >> 2, sl0 = tid & 3;        // i=0: rows 0..63
  const unsigned short* a0 = A + (size_t)(m0 + row0) * 1024 + sl0 * 8;
  const unsigned short* a1 = A + (size_t)(m0 + 64 + row0) * 1024 + sl0 * 8;
  const unsigned short* b0 = Bt + (size_t)(n0 + row0) * 1024 + sl0 * 8;
  const unsigned short* b1 = Bt + (size_t)(n0 + 64 + row0) * 1024 + sl0 * 8;
  char* adst = (char*)As + wid * 64 * 16;   // +4096 rows-half, +8192 sub, +16384 buf
  char* bdst = (char*)Bs + wid * 64 * 16;

  auto STAGE = [&](int buf) {  // stages one BK=64 K-step (both subs); advances
    const int bo = buf * 16384;
    gload_lds16(a0,      adst + bo);
    gload_lds16(a1,      adst + bo + 4096);
    gload_lds16(a0 + 32, adst + bo + 8192);
    gload_lds16(a1 + 32, adst + bo + 8192 + 4096);
    gload_lds16(b0,      bdst + bo);
    gload_lds16(b1,      bdst + bo + 4096);
    gload_lds16(b0 + 32, bdst + bo + 8192);
    gload_lds16(b1 + 32, bdst + bo + 8192 + 4096);
    a0 += 64; a1 += 64; b0 += 64; b1 += 64;
  };

  f32x4 zero4 = {0.f, 0.f, 0.f, 0.f};
  f32x4 acc[4][4];
#pragma unroll
  for (int mi = 0; mi < 4; ++mi)
#pragma unroll
    for (int ni = 0; ni < 4; ++ni) acc[mi][ni] = zero4;

  STAGE(0);
  asm volatile("s_waitcnt vmcnt(0)" ::: "memory");
  __builtin_amdgcn_s_barrier();

  for (int t = 0; t < 16; ++t) {
    const int cur = t & 1;
    if (t < 15) STAGE(cur ^ 1);        // issue next K-step's loads early
#pragma unroll
    for (int sub = 0; sub < 2; ++sub) {
      short8 af[4], bf[4];
#pragma unroll
      for (int mi = 0; mi < 4; ++mi)
        af[mi] = *(const short8*)&As[cur][sub][(wr * 64 + mi * 16 + r) * 32 + g * 8];
#pragma unroll
      for (int ni = 0; ni < 4; ++ni)
        bf[ni] = *(const short8*)&Bs[cur][sub][(wc * 64 + ni * 16 + r) * 32 + g * 8];
#pragma unroll
      for (int mi = 0; mi < 4; ++mi)
#pragma unroll
        for (int ni = 0; ni < 4; ++ni)
          acc[mi][ni] = __builtin_amdgcn_mfma_f32_16x16x32_bf16(
              af[mi], bf[ni], acc[mi][ni], 0, 0, 0);
    }
    asm volatile("s_waitcnt vmcnt(0)" ::: "memory");  // next-step loads landed
    __builtin_amdgcn_s_barrier();
  }

#pragma unroll
  for (int mi = 0; mi < 4; ++mi) {
#pragma unroll
    for (int ni = 0; ni < 4; ++ni) {
      const int n = n0 + wc * 64 + ni * 16 + r;
      const float bv = bias[n];
      const int mbase = m0 + wr * 64 + mi * 16 + g * 4;
      if (EPI == 0) {
        const int sec = n >> 10, e = n & 1023, h = e >> 6, dd = e & 63;
        const int b = mbase >> 11, t = mbase & 2047;
        if (sec == 2) {  // V transposed: [B,H,64,2048], 4 consecutive t packed
          ushort4_t pk;
#pragma unroll
          for (int j = 0; j < 4; ++j) pk[j] = f2bf(acc[mi][ni][j] + bv);
          *(ushort4_t*)&VTo[(((size_t)b * 16 + h) * 64 + dd) * 2048 + t] = pk;
        } else {
          unsigned short* dst = (sec == 0) ? Qo : Ko;
          const float scl = (sec == 0) ? QSCALE : 1.0f;  // fold softmax scale
#pragma unroll
          for (int j = 0; j < 4; ++j)
            dst[(((size_t)b * 16 + h) * 2048 + t + j) * 64 + dd] =
                f2bf((acc[mi][ni][j] + bv) * scl);
        }
      } else {
#pragma unroll
        for (int j = 0; j < 4; ++j)
          Out[(size_t)(mbase + j) * 1024 + n] = acc[mi][ni][j] + bv;
      }
    }
  }
}

// ------------------------------------------------------------ flash attention
// 1D grid 512, XCD-swizzled. 8 waves; wave owns 32 q-rows x ALL keys.
// KVBLK=128 as two 64-key sub-tiles per barrier (16 iterations). REG-STAGED
// (coalesced rows) -> ds_write to dual-conflict-free XOR layout right after
// QK-A -> lane-cyclic conflict-free fragment reads. launch_bounds(512,2):
// occupancy grid-limited at 2 blocks/CU, so 128-VGPR budget is free (no spill).
// Basis-free softmax; all-ones-MFMA row-sum.
__global__ __launch_bounds__(512, 2) void k_attn(
    const unsigned short* __restrict__ Qg, const unsigned short* __restrict__ Kg,
    const unsigned short* __restrict__ VTg, const int* __restrict__ maskp,
    unsigned short* __restrict__ ctx) {
  __shared__ unsigned short Ks[2 * 8192];     // [buf][sub][512 slots x 16B]
  __shared__ unsigned short Vs[2 * 8192];
  const int tid = threadIdx.x, lane = tid & 63, wid = tid >> 6;
  const int q = lane & 31, hi = lane >> 5;
  const int id = blockIdx.x;
  const int slot = id >> 3;
  const int bh = (id & 7) * 8 + (slot >> 3);
  const int b = bh >> 4, h = bh & 15;
  const int q0 = (slot & 7) * 256 + wid * 32;
  const int qr = q0 + q;

  const unsigned short* Qb = Qg + (size_t)bh * SEQ * 64;
  const unsigned short* Kb = Kg + (size_t)bh * SEQ * 64;
  const unsigned short* Vb = VTg + (size_t)bh * 64 * SEQ;
  const int* mb = maskp + b * SEQ;

  // reg-staging geometry: thread t -> row t>>3, chunk c=t&7 (coalesced rows);
  // sub-B = K rows +64 / V keys +64, same pslot in its own 8KB slab.
  const int srow = tid >> 3, sc = tid & 7;
  const unsigned short* kp = Kb + srow * 64 + sc * 8;            // +8192/tile
  const unsigned short* vp = Vb + (size_t)srow * SEQ + sc * 8;   // +128/tile
  // phys slot = [(c>>1)*128 + (row>>5)*64 + (c&1)*32 + (row&31)] ^ (c&7)
  const int pslot = ((sc >> 1) * 128 + (srow >> 5) * 64 + (sc & 1) * 32 +
                     (srow & 31)) ^ (sc & 7);
  char* kw = (char*)Ks + pslot * 16;          // + buf*16384, + sub*8192
  char* vw = (char*)Vs + pslot * 16;

  // Q fragments (B-operand of S^T mfma): lane holds Q[qr][ds*16 + hi*8 + 0..7]
  short8 qf[4];
#pragma unroll
  for (int ds = 0; ds < 4; ++ds)
    qf[ds] = *(const short8*)&Qb[(size_t)qr * 64 + ds * 16 + hi * 8];

  // all-ones bf16 A-fragment (constant matrix => fragment-layout-proof)
  short8 onesf;
#pragma unroll
  for (int j = 0; j < 8; ++j) onesf[j] = (short)0x3F80;

  f32x16 z16 = {0.f,0.f,0.f,0.f,0.f,0.f,0.f,0.f,0.f,0.f,0.f,0.f,0.f,0.f,0.f,0.f};
  f32x16 o0 = z16, o1 = z16;   // O^T[dd][q]: dd = (i&3)+8*(i>>2)+4*hi (+32)
  f32x16 osum = z16;           // every component = sum_k P[q][k] (all rows =)
  const int kb4 = hi * 4;

  // the verified 64-key compute block (QK^T -> exp2 -> pf -> PV+osum)
  auto COMPUTE = [&](const char* KsB, const char* VsB,
                     unsigned long long bits) {
    f32x16 c0 = z16, c1 = z16;
    __builtin_amdgcn_s_setprio(1);
#pragma unroll
    for (int ds = 0; ds < 4; ++ds) {
      const int ko = (lane ^ ((ds * 2 + hi) & 7)) * 16 + ds * 2048;
      short8 ka0 = *(const short8*)(KsB + ko);
      short8 ka1 = *(const short8*)(KsB + ko + 1024);
      c0 = __builtin_amdgcn_mfma_f32_32x32x16_bf16(ka0, qf[ds], c0, 0, 0, 0);
      c1 = __builtin_amdgcn_mfma_f32_32x32x16_bf16(ka1, qf[ds], c1, 0, 0, 0);
    }
    __builtin_amdgcn_s_setprio(0);

#pragma unroll
    for (int i = 0; i < 16; ++i) {
      c0[i] = exp2_raw(c0[i]);
      c1[i] = exp2_raw(c1[i]);
    }
    if (bits != ~0ull) {  // wave-uniform: only when mask has zeros
#pragma unroll
      for (int i = 0; i < 16; ++i) {
        const int k0 = (i & 3) + 8 * (i >> 2) + kb4;
        if (!((bits >> k0) & 1)) c0[i] = 0.f;
        if (!((bits >> (k0 + 32)) & 1)) c1[i] = 0.f;
      }
    }

    short8 pf[4];
#pragma unroll
    for (int sub = 0; sub < 2; ++sub) {
      uint32_t w[8];
#pragma unroll
      for (int j = 0; j < 8; ++j)
        w[j] = sub ? cvtpk(c1[2 * j], c1[2 * j + 1])
                   : cvtpk(c0[2 * j], c0[2 * j + 1]);
      asm("v_permlane32_swap_b32 %0, %1" : "+v"(w[0]), "+v"(w[2]));
      asm("v_permlane32_swap_b32 %0, %1" : "+v"(w[1]), "+v"(w[3]));
      asm("v_permlane32_swap_b32 %0, %1" : "+v"(w[4]), "+v"(w[6]));
      asm("v_permlane32_swap_b32 %0, %1" : "+v"(w[5]), "+v"(w[7]));
      union { uint32_t u[4]; short8 s; } ua, ub;
      ua.u[0] = w[0]; ua.u[1] = w[1]; ua.u[2] = w[2]; ua.u[3] = w[3];
      ub.u[0] = w[4]; ub.u[1] = w[5]; ub.u[2] = w[6]; ub.u[3] = w[7];
      pf[sub * 2] = ua.s;
      pf[sub * 2 + 1] = ub.s;
    }

    __builtin_amdgcn_s_setprio(1);
#pragma unroll
    for (int ks = 0; ks < 4; ++ks) {
      const int vo = (lane ^ ((ks * 2 + hi) & 7)) * 16 + ks * 2048;
      short8 va0 = *(const short8*)(VsB + vo);
      short8 va1 = *(const short8*)(VsB + vo + 1024);
      o0 = __builtin_amdgcn_mfma_f32_32x32x16_bf16(va0, pf[ks], o0, 0, 0, 0);
      o1 = __builtin_amdgcn_mfma_f32_32x32x16_bf16(va1, pf[ks], o1, 0, 0, 0);
      osum = __builtin_amdgcn_mfma_f32_32x32x16_bf16(onesf, pf[ks], osum,
                                                     0, 0, 0);
    }
    __builtin_amdgcn_s_setprio(0);
  };

  // prologue: stage tile 0 (both sub-tiles) through registers into buf 0
  {
    short8 kA = *(const short8*)kp;
    short8 kB = *(const short8*)(kp + 4096);
    short8 vA = *(const short8*)vp;
    short8 vB = *(const short8*)(vp + 64);
    kp += 8192; vp += 128;
    *(short8*)kw = kA;            *(short8*)(kw + 8192) = kB;
    *(short8*)vw = vA;            *(short8*)(vw + 8192) = vB;
  }
  const int* mptr = mb + lane;
  int mv0 = mptr[0], mv1 = mptr[64];
  mptr += 128;
  __syncthreads();

  for (int t = 0; t < 16; ++t) {
    const int cur = t & 1;
    // unconditional loads of tile t+1 (t=15 reloads tile 15 -> discarded)
    short8 kA = *(const short8*)kp;
    short8 kB = *(const short8*)(kp + 4096);
    short8 vA = *(const short8*)vp;
    short8 vB = *(const short8*)(vp + 64);
    const int mn0 = mptr[0], mn1 = mptr[64];
    if (t < 14) { kp += 8192; vp += 128; mptr += 128; }
    const unsigned long long bits0 = __ballot(mv0 != 0);
    const unsigned long long bits1 = __ballot(mv1 != 0);
    mv0 = mn0; mv1 = mn1;

    const char* KsC = (const char*)Ks + cur * 16384;
    const char* VsC = (const char*)Vs + cur * 16384;

    // sub-tile A compute; staged-reg writes right after its QK (inside
    // COMPUTE the QK comes first, so place writes between the two calls
    // is too late for latency -> write after issuing A's QK via split:
    COMPUTE(KsC, VsC, bits0);

    // write tile t+1 into buf cur^1 (safe since end-of-prev-iter barrier;
    // A's compute above hid the L2 load latency; short live ranges)
    {
      const int bo = (cur ^ 1) * 16384;
      *(short8*)(kw + bo) = kA;          *(short8*)(kw + bo + 8192) = kB;
      *(short8*)(vw + bo) = vA;          *(short8*)(vw + bo + 8192) = vB;
    }

    // sub-tile B compute
    COMPUTE(KsC + 8192, VsC + 8192, bits1);

    __syncthreads();
  }

  // ctx [B,T,1024] bf16: lane writes its query row qr, dd groups of 4
  const float inv = 1.f / osum[0];
#pragma unroll
  for (int ns = 0; ns < 2; ++ns) {
#pragma unroll
    for (int g_ = 0; g_ < 4; ++g_) {
      ushort4_t v4;
#pragma unroll
      for (int e = 0; e < 4; ++e) {
        const float val = (ns ? o1[g_ * 4 + e] : o0[g_ * 4 + e]) * inv;
        v4[e] = f2bf(val);
      }
      *(ushort4_t*)&ctx[((size_t)b * SEQ + qr) * 1024 + h * 64 + ns * 32 +
                        g_ * 8 + hi * 4] = v4;
    }
  }
}

// ---------------------------------------------------------------------------
extern "C" void kernel_launch(void* const* d_in, const int* in_sizes, int n_in,
                              void* d_out, int out_size, void* d_ws,
                              size_t ws_size, hipStream_t stream) {
  const float* x = (const float*)d_in[0];
  const int* mask = (const int*)d_in[1];
  const float* Wqkv = (const float*)d_in[2];
  const float* bqkv = (const float*)d_in[3];
  const float* Wout = (const float*)d_in[4];
  const float* bout = (const float*)d_in[5];
  float* out = (float*)d_out;

  unsigned short* ws = (unsigned short*)d_ws;
  unsigned short* xb = ws;                       // 8388608 (reused as ctx)
  unsigned short* wqt = ws + 8388608;            // 3145728
  unsigned short* wot = ws + 11534336;           // 1048576
  unsigned short* Q = ws + 12582912;             // 8388608
  unsigned short* K = ws + 20971520;             // 8388608
  unsigned short* VT = ws + 29360128;            // 8388608
  unsigned short* ctx = xb;

  k_prep<<<8192, 256, 0, stream>>>(x, xb, Wqkv, wqt, Wout, wot);
  k_gemm<0, 24><<<dim3(24, 64), 256, 0, stream>>>(xb, wqt, bqkv, Q, K, VT,
                                                  nullptr);
  k_attn<<<512, 512, 0, stream>>>(Q, K, VT, mask, ctx);
  k_gemm<1, 8><<<dim3(8, 64), 256, 0, stream>>>(ctx, wot, bout, nullptr,
                                                nullptr, nullptr, out);
}